// Round 2
// baseline (83.476 us; speedup 1.0000x reference)
//
#include <hip/hip_runtime.h>
#include <math.h>

// Problem constants (match reference)
#define B_  4
#define C_  128
#define H_  240
#define W_  320
#define N_  1024
#define NPTS (B_ * N_)          // 4096
#define HW_ (H_ * W_)

__device__ __forceinline__ float wave_reduce(float v) {
    // 64-lane butterfly sum
    #pragma unroll
    for (int off = 32; off > 0; off >>= 1)
        v += __shfl_xor(v, off, 64);
    return v;
}

// One WAVE per point; lane l owns channels l and l+64.
// 128-thread blocks = 2 points per block, no LDS, no __syncthreads.
__global__ __launch_bounds__(128) void gn_point_kernel(
    const float* __restrict__ Fa, const float* __restrict__ Fb,
    const float* __restrict__ ma, const float* __restrict__ mb,
    const float* __restrict__ noise,
    float* __restrict__ ws_e1, float* __restrict__ ws_ld)
{
    const int wid  = threadIdx.x >> 6;       // wave in block (0/1)
    const int lane = threadIdx.x & 63;
    const int p = (blockIdx.x << 1) | wid;   // point 0..4095
    const int b = p >> 10;                   // batch

    const float inv_level = 0.125f;
    const float xa  = ma[p * 2 + 0] * inv_level;
    const float ya  = ma[p * 2 + 1] * inv_level;
    const float ubx = mb[p * 2 + 0] * inv_level;
    const float uby = mb[p * 2 + 1] * inv_level;
    const float xs  = 2.0f * noise[p * 2 + 0] - 1.0f + ubx;
    const float ys  = 2.0f * noise[p * 2 + 1] - 1.0f + uby;

    // ---- F_a bilinear indices ----
    const float ax0f = floorf(xa), ay0f = floorf(ya);
    const float awx = xa - ax0f, awy = ya - ay0f;
    const int ax0 = min(max((int)ax0f, 0), W_ - 1);
    const int ax1 = min(ax0 + 1, W_ - 1);
    const int ay0 = min(max((int)ay0f, 0), H_ - 1);
    const int ay1 = min(ay0 + 1, H_ - 1);

    // ---- F_b patch indices ----
    const float bx0f = floorf(xs), by0f = floorf(ys);
    const float wx = xs - bx0f, wy = ys - by0f;
    const int x0 = min(max((int)bx0f, 0), W_ - 1);
    const int x1 = min(x0 + 1, W_ - 1);
    const int y0 = min(max((int)by0f, 0), H_ - 1);
    const int y1 = min(y0 + 1, H_ - 1);
    const int xm = max(x0 - 1, 0);
    const int xp = min(x1 + 1, W_ - 1);
    const int ym = max(y0 - 1, 0);
    const int yp = min(y1 + 1, H_ - 1);

    const int o_y0 = y0 * W_, o_y1 = y1 * W_;
    const int o_ym = ym * W_, o_yp = yp * W_;
    const int o_a0 = ay0 * W_, o_a1 = ay1 * W_;

    // channel planes: c0 = lane, c1 = lane + 64
    const size_t plane = ((size_t)b * C_ + lane) * HW_;
    const float* __restrict__ fa0 = Fa + plane;
    const float* __restrict__ fa1 = fa0 + (size_t)64 * HW_;
    const float* __restrict__ fb0 = Fb + plane;
    const float* __restrict__ fb1 = fb0 + (size_t)64 * HW_;

    // ---------- 32 independent gathers, hoisted into one cluster ----------
    const float A00_0 = fa0[o_a0 + ax0], A01_0 = fa0[o_a0 + ax1];
    const float A10_0 = fa0[o_a1 + ax0], A11_0 = fa0[o_a1 + ax1];
    const float r0m_0 = fb0[o_y0 + xm],  r00_0 = fb0[o_y0 + x0];
    const float r01_0 = fb0[o_y0 + x1],  r0p_0 = fb0[o_y0 + xp];
    const float r1m_0 = fb0[o_y1 + xm],  r10_0 = fb0[o_y1 + x0];
    const float r11_0 = fb0[o_y1 + x1],  r1p_0 = fb0[o_y1 + xp];
    const float rm0_0 = fb0[o_ym + x0],  rm1_0 = fb0[o_ym + x1];
    const float rp0_0 = fb0[o_yp + x0],  rp1_0 = fb0[o_yp + x1];

    const float A00_1 = fa1[o_a0 + ax0], A01_1 = fa1[o_a0 + ax1];
    const float A10_1 = fa1[o_a1 + ax0], A11_1 = fa1[o_a1 + ax1];
    const float r0m_1 = fb1[o_y0 + xm],  r00_1 = fb1[o_y0 + x0];
    const float r01_1 = fb1[o_y0 + x1],  r0p_1 = fb1[o_y0 + xp];
    const float r1m_1 = fb1[o_y1 + xm],  r10_1 = fb1[o_y1 + x0];
    const float r11_1 = fb1[o_y1 + x1],  r1p_1 = fb1[o_y1 + xp];
    const float rm0_1 = fb1[o_ym + x0],  rm1_1 = fb1[o_ym + x1];
    const float rp0_1 = fb1[o_yp + x0],  rp1_1 = fb1[o_yp + x1];

    // ---------- weights ----------
    const float aw00 = (1.f - awx) * (1.f - awy);
    const float aw01 = awx * (1.f - awy);
    const float aw10 = (1.f - awx) * awy;
    const float aw11 = awx * awy;
    const float w00 = (1.f - wx) * (1.f - wy);
    const float w01 = wx * (1.f - wy);
    const float w10 = (1.f - wx) * wy;
    const float w11 = wx * wy;

    float vals[9];
    #pragma unroll
    for (int k = 0; k < 9; ++k) vals[k] = 0.f;

    // ---------- per-channel interpolation + products ----------
    #pragma unroll
    for (int ch = 0; ch < 2; ++ch) {
        float ft, fs, jx, jy;
        if (ch == 0) {
            ft = A00_0 * aw00 + A01_0 * aw01 + A10_0 * aw10 + A11_0 * aw11;
            fs = r00_0 * w00 + r01_0 * w01 + r10_0 * w10 + r11_0 * w11;
            jx = 0.5f * ((r01_0 - r0m_0) * w00 + (r0p_0 - r00_0) * w01
                       + (r11_0 - r1m_0) * w10 + (r1p_0 - r10_0) * w11);
            jy = 0.5f * ((r10_0 - rm0_0) * w00 + (r11_0 - rm1_0) * w01
                       + (rp0_0 - r00_0) * w10 + (rp1_0 - r01_0) * w11);
        } else {
            ft = A00_1 * aw00 + A01_1 * aw01 + A10_1 * aw10 + A11_1 * aw11;
            fs = r00_1 * w00 + r01_1 * w01 + r10_1 * w10 + r11_1 * w11;
            jx = 0.5f * ((r01_1 - r0m_1) * w00 + (r0p_1 - r00_1) * w01
                       + (r11_1 - r1m_1) * w10 + (r1p_1 - r10_1) * w11);
            jy = 0.5f * ((r10_1 - rm0_1) * w00 + (r11_1 - rm1_1) * w01
                       + (rp0_1 - r00_1) * w10 + (rp1_1 - r01_1) * w11);
        }
        vals[0] += ft * ft;
        vals[1] += fs * fs;
        vals[2] += jx * fs;
        vals[3] += jx * ft;
        vals[4] += jy * fs;
        vals[5] += jy * ft;
        vals[6] += jx * jx;
        vals[7] += jx * jy;
        vals[8] += jy * jy;
    }

    // ---------- 9 wave reductions (no LDS, no barrier) ----------
    #pragma unroll
    for (int k = 0; k < 9; ++k)
        vals[k] = wave_reduce(vals[k]);

    if (lane == 0) {
        const float nt = fmaxf(sqrtf(vals[0]), 1e-12f);
        const float ns = fmaxf(sqrtf(vals[1]), 1e-12f);
        const float b0 = vals[2] / ns - vals[3] / nt;
        const float b1 = vals[4] / ns - vals[5] / nt;
        const float H00 = vals[6] + 1e-9f;
        const float H01 = vals[7];
        const float H11 = vals[8] + 1e-9f;
        const float det = H00 * H11 - H01 * H01;
        const float inv = 1.0f / det;
        const float u0 = (H11 * b0 - H01 * b1) * inv;   // (Hinv @ b)[0]
        const float u1 = (H00 * b1 - H01 * b0) * inv;   // (Hinv @ b)[1]
        const float d0 = (ubx - xs) + u0;               // diff = ub - miu
        const float d1 = (uby - ys) + u1;
        const float quad = d0 * (H00 * d0 + H01 * d1) + d1 * (H01 * d0 + H11 * d1);
        ws_e1[p] = 0.5f * quad;
        ws_ld[p] = logf(det);
    }
}

// Single-block deterministic reduction of the 4096 per-point partials.
__global__ __launch_bounds__(256) void gn_reduce_kernel(
    const float* __restrict__ ws_e1, const float* __restrict__ ws_ld,
    float* __restrict__ out)
{
    __shared__ double sm1[256];
    __shared__ double sm2[256];
    double a1 = 0.0, a2 = 0.0;
    for (int i = threadIdx.x; i < NPTS; i += 256) {
        a1 += (double)ws_e1[i];
        a2 += (double)ws_ld[i];
    }
    sm1[threadIdx.x] = a1;
    sm2[threadIdx.x] = a2;
    __syncthreads();
    for (int s = 128; s > 0; s >>= 1) {
        if (threadIdx.x < s) {
            sm1[threadIdx.x] += sm1[threadIdx.x + s];
            sm2[threadIdx.x] += sm2[threadIdx.x + s];
        }
        __syncthreads();
    }
    if (threadIdx.x == 0) {
        const double e1 = sm1[0];
        const double sum_ld = sm2[0];
        const double log2pi = (double)logf(6.283185307179586f);
        const double e2 = (double)NPTS * log2pi - 0.5 * sum_ld;
        const double e = 1.0 * e1 + (2.0 / 7.0) * e2;   // E1_LAMDA=1, E2_LAMDA=2/7
        out[0] = (float)(0.3 * e);                      // GN_LAMDA * e
        out[1] = (float)e1;
        out[2] = (float)e2;
    }
}

extern "C" void kernel_launch(void* const* d_in, const int* in_sizes, int n_in,
                              void* d_out, int out_size, void* d_ws, size_t ws_size,
                              hipStream_t stream) {
    const float* Fa    = (const float*)d_in[0];
    const float* Fb    = (const float*)d_in[1];
    const float* ma    = (const float*)d_in[2];
    const float* mb    = (const float*)d_in[3];
    const float* noise = (const float*)d_in[4];
    float* out = (float*)d_out;

    float* ws_e1 = (float*)d_ws;          // 4096 floats
    float* ws_ld = ws_e1 + NPTS;          // 4096 floats

    gn_point_kernel<<<NPTS / 2, 128, 0, stream>>>(Fa, Fb, ma, mb, noise, ws_e1, ws_ld);
    gn_reduce_kernel<<<1, 256, 0, stream>>>(ws_e1, ws_ld, out);
}

// Round 3
// 70.371 us; speedup vs baseline: 1.1862x; 1.1862x over previous
//
#include <hip/hip_runtime.h>
#include <math.h>

// Problem constants (match reference)
#define B_  4
#define C_  128
#define H_  240
#define W_  320
#define N_  1024
#define NPTS (B_ * N_)          // 4096
#define HW_ (H_ * W_)

typedef float f4 __attribute__((ext_vector_type(4)));
typedef float f2 __attribute__((ext_vector_type(2)));

__device__ __forceinline__ f4 load4(const float* p) {
    f4 v;
    __builtin_memcpy(&v, p, 16);   // align-4 dwordx4
    return v;
}
__device__ __forceinline__ f2 load2(const float* p) {
    f2 v;
    __builtin_memcpy(&v, p, 8);    // align-4 dwordx2
    return v;
}

__device__ __forceinline__ float wave_reduce(float v) {
    #pragma unroll
    for (int off = 32; off > 0; off >>= 1)
        v += __shfl_xor(v, off, 64);
    return v;
}

// One WAVE per point; lane l owns channels l and l+64.
// 256-thread blocks = 4 points per block, no LDS, no __syncthreads.
__global__ __launch_bounds__(256) void gn_point_kernel(
    const float* __restrict__ Fa, const float* __restrict__ Fb,
    const float* __restrict__ ma, const float* __restrict__ mb,
    const float* __restrict__ noise,
    float* __restrict__ ws_e1, float* __restrict__ ws_ld)
{
    const int wid  = threadIdx.x >> 6;        // wave in block (0..3)
    const int lane = threadIdx.x & 63;
    const int p = (blockIdx.x << 2) | wid;    // point 0..4095
    const int b = p >> 10;                    // batch

    const float inv_level = 0.125f;
    const float xa  = ma[p * 2 + 0] * inv_level;
    const float ya  = ma[p * 2 + 1] * inv_level;
    const float ubx = mb[p * 2 + 0] * inv_level;
    const float uby = mb[p * 2 + 1] * inv_level;
    const float xs  = 2.0f * noise[p * 2 + 0] - 1.0f + ubx;
    const float ys  = 2.0f * noise[p * 2 + 1] - 1.0f + uby;

    // ---- F_a bilinear indices (interior guaranteed; clamp for safety) ----
    const float ax0f = floorf(xa), ay0f = floorf(ya);
    const float awx = xa - ax0f, awy = ya - ay0f;
    const int ax0 = min(max((int)ax0f, 0), W_ - 2);
    const int ay0 = min(max((int)ay0f, 0), H_ - 2);

    // ---- F_b patch indices (interior guaranteed: x0 in [1,W-3], y0 in [1,H-3]) ----
    const float bx0f = floorf(xs), by0f = floorf(ys);
    const float wx = xs - bx0f, wy = ys - by0f;
    const int x0 = min(max((int)bx0f, 1), W_ - 3);
    const int y0 = min(max((int)by0f, 1), H_ - 3);
    const int xm = x0 - 1;                   // row vector start: xm..x0+2 (4 floats)
    const int ym = y0 - 1;
    const int y1 = y0 + 1;
    const int yp = y0 + 2;

    const int o_y0 = y0 * W_ + xm;           // 4-float row at y0
    const int o_y1 = y1 * W_ + xm;           // 4-float row at y1
    const int o_ym = ym * W_ + x0;           // 2-float row at ym
    const int o_yp = yp * W_ + x0;           // 2-float row at yp
    const int o_a0 = ay0 * W_ + ax0;         // 2-float row at ay0
    const int o_a1 = (ay0 + 1) * W_ + ax0;   // 2-float row at ay1

    // channel planes: c0 = lane, c1 = lane + 64
    const size_t plane = ((size_t)b * C_ + lane) * HW_;
    const float* __restrict__ fa0 = Fa + plane;
    const float* __restrict__ fa1 = fa0 + (size_t)64 * HW_;
    const float* __restrict__ fb0 = Fb + plane;
    const float* __restrict__ fb1 = fb0 + (size_t)64 * HW_;

    // ---------- 12 independent vector gathers (64B/lane/channel-pair) ----------
    const f4 row0_0 = load4(fb0 + o_y0);
    const f4 row1_0 = load4(fb0 + o_y1);
    const f2 rm_0   = load2(fb0 + o_ym);
    const f2 rp_0   = load2(fb0 + o_yp);
    const f2 a0_0   = load2(fa0 + o_a0);
    const f2 a1_0   = load2(fa0 + o_a1);

    const f4 row0_1 = load4(fb1 + o_y0);
    const f4 row1_1 = load4(fb1 + o_y1);
    const f2 rm_1   = load2(fb1 + o_ym);
    const f2 rp_1   = load2(fb1 + o_yp);
    const f2 a0_1   = load2(fa1 + o_a0);
    const f2 a1_1   = load2(fa1 + o_a1);

    // ---------- weights ----------
    const float aw00 = (1.f - awx) * (1.f - awy);
    const float aw01 = awx * (1.f - awy);
    const float aw10 = (1.f - awx) * awy;
    const float aw11 = awx * awy;
    const float w00 = (1.f - wx) * (1.f - wy);
    const float w01 = wx * (1.f - wy);
    const float w10 = (1.f - wx) * wy;
    const float w11 = wx * wy;

    float vals[9];
    #pragma unroll
    for (int k = 0; k < 9; ++k) vals[k] = 0.f;

    #pragma unroll
    for (int ch = 0; ch < 2; ++ch) {
        const f4 row0 = ch ? row0_1 : row0_0;
        const f4 row1 = ch ? row1_1 : row1_0;
        const f2 rm   = ch ? rm_1   : rm_0;
        const f2 rp   = ch ? rp_1   : rp_0;
        const f2 a0   = ch ? a0_1   : a0_0;
        const f2 a1   = ch ? a1_1   : a1_0;

        const float ft = a0.x * aw00 + a0.y * aw01 + a1.x * aw10 + a1.y * aw11;
        const float fs = row0.y * w00 + row0.z * w01 + row1.y * w10 + row1.z * w11;
        const float jx = 0.5f * ((row0.z - row0.x) * w00 + (row0.w - row0.y) * w01
                               + (row1.z - row1.x) * w10 + (row1.w - row1.y) * w11);
        const float jy = 0.5f * ((row1.y - rm.x) * w00 + (row1.z - rm.y) * w01
                               + (rp.x - row0.y) * w10 + (rp.y - row0.z) * w11);

        vals[0] += ft * ft;
        vals[1] += fs * fs;
        vals[2] += jx * fs;
        vals[3] += jx * ft;
        vals[4] += jy * fs;
        vals[5] += jy * ft;
        vals[6] += jx * jx;
        vals[7] += jx * jy;
        vals[8] += jy * jy;
    }

    // ---------- 9 wave reductions (no LDS, no barrier) ----------
    #pragma unroll
    for (int k = 0; k < 9; ++k)
        vals[k] = wave_reduce(vals[k]);

    if (lane == 0) {
        const float nt = fmaxf(sqrtf(vals[0]), 1e-12f);
        const float ns = fmaxf(sqrtf(vals[1]), 1e-12f);
        const float b0 = vals[2] / ns - vals[3] / nt;
        const float b1 = vals[4] / ns - vals[5] / nt;
        const float H00 = vals[6] + 1e-9f;
        const float H01 = vals[7];
        const float H11 = vals[8] + 1e-9f;
        const float det = H00 * H11 - H01 * H01;
        const float inv = 1.0f / det;
        const float u0 = (H11 * b0 - H01 * b1) * inv;   // (Hinv @ b)[0]
        const float u1 = (H00 * b1 - H01 * b0) * inv;   // (Hinv @ b)[1]
        const float d0 = (ubx - xs) + u0;               // diff = ub - miu
        const float d1 = (uby - ys) + u1;
        const float quad = d0 * (H00 * d0 + H01 * d1) + d1 * (H01 * d0 + H11 * d1);
        ws_e1[p] = 0.5f * quad;
        ws_ld[p] = logf(det);
    }
}

// Single-block deterministic reduction of the 4096 per-point partials.
__global__ __launch_bounds__(256) void gn_reduce_kernel(
    const float* __restrict__ ws_e1, const float* __restrict__ ws_ld,
    float* __restrict__ out)
{
    __shared__ double sm1[256];
    __shared__ double sm2[256];
    double a1 = 0.0, a2 = 0.0;
    for (int i = threadIdx.x; i < NPTS; i += 256) {
        a1 += (double)ws_e1[i];
        a2 += (double)ws_ld[i];
    }
    sm1[threadIdx.x] = a1;
    sm2[threadIdx.x] = a2;
    __syncthreads();
    for (int s = 128; s > 0; s >>= 1) {
        if (threadIdx.x < s) {
            sm1[threadIdx.x] += sm1[threadIdx.x + s];
            sm2[threadIdx.x] += sm2[threadIdx.x + s];
        }
        __syncthreads();
    }
    if (threadIdx.x == 0) {
        const double e1 = sm1[0];
        const double sum_ld = sm2[0];
        const double log2pi = (double)logf(6.283185307179586f);
        const double e2 = (double)NPTS * log2pi - 0.5 * sum_ld;
        const double e = 1.0 * e1 + (2.0 / 7.0) * e2;   // E1_LAMDA=1, E2_LAMDA=2/7
        out[0] = (float)(0.3 * e);                      // GN_LAMDA * e
        out[1] = (float)e1;
        out[2] = (float)e2;
    }
}

extern "C" void kernel_launch(void* const* d_in, const int* in_sizes, int n_in,
                              void* d_out, int out_size, void* d_ws, size_t ws_size,
                              hipStream_t stream) {
    const float* Fa    = (const float*)d_in[0];
    const float* Fb    = (const float*)d_in[1];
    const float* ma    = (const float*)d_in[2];
    const float* mb    = (const float*)d_in[3];
    const float* noise = (const float*)d_in[4];
    float* out = (float*)d_out;

    float* ws_e1 = (float*)d_ws;          // 4096 floats
    float* ws_ld = ws_e1 + NPTS;          // 4096 floats

    gn_point_kernel<<<NPTS / 4, 256, 0, stream>>>(Fa, Fb, ma, mb, noise, ws_e1, ws_ld);
    gn_reduce_kernel<<<1, 256, 0, stream>>>(ws_e1, ws_ld, out);
}